// Round 9
// baseline (66.923 us; speedup 1.0000x reference)
//
#include <hip/hip_runtime.h>
#include <hip/hip_bf16.h>
#include <cstdint>

#define B_ROWS 8192
#define DIM    1024
#define NC     8
#define NXCD   8
#define SLOTS  16    // per-XCD 128-row tile slots (16*128 = 2048 rows/cond primary)
#define BM     128
#define BN     128
#define NT     16    // K tiles (DIM/64)

typedef __bf16 bf16;
typedef __bf16 bf16x8 __attribute__((ext_vector_type(8)));
typedef float  f32x4  __attribute__((ext_vector_type(4)));

// ---------------- route: 1024 threads, scan-based, no atomics --------------
__global__ __launch_bounds__(1024) void route_kernel(
    const int* __restrict__ ids, const float* __restrict__ b,
    int* __restrict__ row_list, int* __restrict__ xmeta,
    float* __restrict__ bias_sum) {
    __shared__ int wtot_s[16][NC];
    __shared__ int cnt_s[NC];
    __shared__ int off_s[NC];
    __shared__ int used_s[NXCD];
    __shared__ int novf_s[NC];
    int tid = threadIdx.x, lane = tid & 63, wv = tid >> 6;
    const int per = B_ROWS / 1024;  // 8
    int base = tid * per;

    if (tid < NXCD * SLOTS) xmeta[tid * 3 + 2] = 0;

    const int4* idv = (const int4*)(ids + base);
    int4 v0 = idv[0], v1 = idv[1];
    int myid[8] = {v0.x, v0.y, v0.z, v0.w, v1.x, v1.y, v1.z, v1.w};
    unsigned long long p0 = 0, p1 = 0;
#pragma unroll
    for (int q = 0; q < 8; q++) {
        int id = myid[q];
        unsigned long long one = 1ull << ((id & 3) << 4);
        if (id < 4) p0 += one; else p1 += one;
    }
    unsigned long long i0 = p0, i1 = p1;
#pragma unroll
    for (int d = 1; d < 64; d <<= 1) {
        unsigned long long u0 = __shfl_up(i0, d, 64);
        unsigned long long u1 = __shfl_up(i1, d, 64);
        if (lane >= d) { i0 += u0; i1 += u1; }
    }
    unsigned long long e0 = i0 - p0, e1 = i1 - p1;
    unsigned long long t0 = __shfl(i0, 63, 64), t1 = __shfl(i1, 63, 64);
    if (lane == 0) {
#pragma unroll
        for (int c = 0; c < 4; c++) {
            wtot_s[wv][c]     = (int)((t0 >> (c << 4)) & 0xFFFF);
            wtot_s[wv][c + 4] = (int)((t1 >> (c << 4)) & 0xFFFF);
        }
    }
    __syncthreads();
    if (tid < NC) {
        int acc = 0;
        for (int w2 = 0; w2 < 16; w2++) { int t = wtot_s[w2][tid]; wtot_s[w2][tid] = acc; acc += t; }
        cnt_s[tid] = acc;
    }
    __syncthreads();
    if (tid < NC) {
        int acc = 0;
        for (int c2 = 0; c2 < tid; c2++) acc += cnt_s[c2];
        off_s[tid] = acc;
    }
    __syncthreads();
    if (tid < 16 * NC) wtot_s[tid >> 3][tid & 7] += off_s[tid & 7];
    __syncthreads();

    if (tid < NC) {  // primary 128-row tiles: condition c -> XCD c
        int c = tid, n = cnt_s[c];
        int tc = (n + BM - 1) >> 7;
        int prim = tc < SLOTS ? tc : SLOTS;
        for (int t = 0; t < prim; t++) {
            int* e = xmeta + (c * SLOTS + t) * 3;
            int rc = n - t * BM; if (rc > BM) rc = BM;
            e[0] = c; e[1] = off_s[c] + t * BM; e[2] = rc;
        }
        used_s[c] = prim;
        novf_s[c] = tc - prim;
    }
    {
        float s = 0.f;
#pragma unroll
        for (int c = 0; c < NC; c++) s += b[c * DIM + tid];
        bias_sum[tid] = s;
    }
    __syncthreads();

    if (tid == 0) {  // overflow tiles (condition with >SLOTS*128 rows)
        int k = 0;
        for (int c = 0; c < NC; c++) {
            for (int t = 0; t < novf_s[c]; t++) {
                for (;;) {
                    int xx = k >> 4, s = k & (SLOTS - 1); k++;
                    if (s >= used_s[xx]) {
                        int* e = xmeta + (xx * SLOTS + s) * 3;
                        int rc = cnt_s[c] - (SLOTS + t) * BM; if (rc > BM) rc = BM;
                        e[0] = c; e[1] = off_s[c] + (SLOTS + t) * BM; e[2] = rc;
                        break;
                    }
                }
            }
        }
    }
    unsigned long long r0 = 0, r1 = 0;
#pragma unroll
    for (int j = 0; j < per; j++) {
        int id = myid[j];
        int sh = (id & 3) << 4;
        unsigned long long run = (id < 4) ? r0 : r1;
        unsigned long long exc = (id < 4) ? e0 : e1;
        int p = wtot_s[wv][id] + (int)((exc >> sh) & 0xFFFF) + (int)((run >> sh) & 0xFFFF);
        row_list[p] = base + j;
        unsigned long long one = 1ull << sh;
        if (id < 4) r0 += one; else r1 += one;
    }
}

// ---------------- fused grouped GEMM: fp32 in, cvt-in-staging --------------
// 128x128 tile, BK=64, 4 waves, reg-staged (global fp32 -> cvt -> swizzled
// ds_write), double-buffered LDS, loads lead by one full K-step (T14).
#define BUFB 32768   // bytes per LDS buffer: (128+128)*64*2
#define ABYT 16384   // A region bytes
__global__ __launch_bounds__(256, 2) void gemm_kernel(
    const float* __restrict__ x, const float* __restrict__ W,
    const float* __restrict__ bias_sum, const int* __restrict__ row_list,
    const int* __restrict__ xmeta, float* __restrict__ out) {
    int xcd = blockIdx.x, slot = blockIdx.y, colt = blockIdx.z;
    const int* e = xmeta + (xcd * SLOTS + slot) * 3;
    int cond = e[0], rstart = e[1], rcnt = e[2];
    if (rcnt == 0) return;
    int col0 = colt * BN;

    __shared__ char lds[2 * BUFB];  // 64 KB double buffer

    int tid  = threadIdx.x;
    int lane = tid & 63;
    int w    = tid >> 6;      // 0..3
    int wr   = w >> 1;        // M half
    int wc   = w & 1;         // N half
    int srow = lane >> 3;     // 0..7
    int g    = lane & 7;      // 16B granule index (8 bf16 cols)

    // global fp32 sources + swizzled LDS write offsets
    const float *aF[4], *bF[4];
    int wofsA[4], wofsB[4];
#pragma unroll
    for (int i = 0; i < 4; i++) {
        int tr = w * 32 + i * 8 + srow;                 // 0..127
        int rr = (tr < rcnt) ? tr : 0;
        int grow = row_list[rstart + rr];
        aF[i] = x + (size_t)grow * DIM + g * 8;
        wofsA[i] = tr * 128 + ((g ^ srow) * 16);        // tr&7 == srow
        int br = w * 32 + i * 8 + srow;
        bF[i] = W + (size_t)cond * DIM * DIM + (size_t)(col0 + br) * DIM + g * 8;
        wofsB[i] = ABYT + br * 128 + ((g ^ srow) * 16);
    }

    f32x4 acc[4][4];
#pragma unroll
    for (int m = 0; m < 4; m++)
#pragma unroll
        for (int n = 0; n < 4; n++) acc[m][n] = (f32x4){0.f, 0.f, 0.f, 0.f};

    int fr = lane & 15;
    int fq = lane >> 4;
    int off0 = (fq * 16) ^ ((fr & 7) << 4);
    int off1 = off0 ^ 64;

    float4 va[4][2], vb[4][2];      // staged fp32 (constant-indexed only)

    auto LOAD = [&](int k0) {
#pragma unroll
        for (int i = 0; i < 4; i++) {
            va[i][0] = *(const float4*)(aF[i] + k0);
            va[i][1] = *(const float4*)(aF[i] + k0 + 4);
            vb[i][0] = *(const float4*)(bF[i] + k0);
            vb[i][1] = *(const float4*)(bF[i] + k0 + 4);
        }
    };
    auto WRITE = [&](int buf) {
#pragma unroll
        for (int i = 0; i < 4; i++) {
            bf16x8 oa, ob;
            oa[0] = (bf16)va[i][0].x; oa[1] = (bf16)va[i][0].y;
            oa[2] = (bf16)va[i][0].z; oa[3] = (bf16)va[i][0].w;
            oa[4] = (bf16)va[i][1].x; oa[5] = (bf16)va[i][1].y;
            oa[6] = (bf16)va[i][1].z; oa[7] = (bf16)va[i][1].w;
            ob[0] = (bf16)vb[i][0].x; ob[1] = (bf16)vb[i][0].y;
            ob[2] = (bf16)vb[i][0].z; ob[3] = (bf16)vb[i][0].w;
            ob[4] = (bf16)vb[i][1].x; ob[5] = (bf16)vb[i][1].y;
            ob[6] = (bf16)vb[i][1].z; ob[7] = (bf16)vb[i][1].w;
            *(bf16x8*)(lds + buf * BUFB + wofsA[i]) = oa;
            *(bf16x8*)(lds + buf * BUFB + wofsB[i]) = ob;
        }
    };

    // prologue: tile 0 staged, tile 1 loads in flight
    LOAD(0);
    WRITE(0);              // compiler inserts fine-grained vmcnt waits
    LOAD(64);
    asm volatile("s_waitcnt lgkmcnt(0)" ::: "memory");
    __builtin_amdgcn_s_barrier();

    for (int t = 0; t < NT; ++t) {
        if (t + 1 < NT) WRITE((t + 1) & 1);       // waits on LOAD(t+1) data
        if (t + 2 < NT) LOAD((t + 2) * 64);       // issue early: one K-step of lead

        const char* bA = lds + (t & 1) * BUFB + (wr * 64 + fr) * 128;
        const char* bB = lds + (t & 1) * BUFB + ABYT + (wc * 64 + fr) * 128;
#pragma unroll
        for (int kk = 0; kk < 2; ++kk) {
            int ofs = kk ? off1 : off0;
            bf16x8 af[4], bv[4];
#pragma unroll
            for (int m = 0; m < 4; m++) af[m] = *(const bf16x8*)(bA + m * 2048 + ofs);
#pragma unroll
            for (int n = 0; n < 4; n++) bv[n] = *(const bf16x8*)(bB + n * 2048 + ofs);
            __builtin_amdgcn_s_setprio(1);
#pragma unroll
            for (int m = 0; m < 4; m++)
#pragma unroll
                for (int n = 0; n < 4; n++)
                    acc[m][n] = __builtin_amdgcn_mfma_f32_16x16x32_bf16(
                        af[m], bv[n], acc[m][n], 0, 0, 0);
            __builtin_amdgcn_s_setprio(0);
        }

        // my ds_writes (next tile) + ds_reads (this tile) retired, then sync
        asm volatile("s_waitcnt lgkmcnt(0)" ::: "memory");
        __builtin_amdgcn_s_barrier();
    }

    float bias[4];
#pragma unroll
    for (int n = 0; n < 4; n++) bias[n] = bias_sum[col0 + wc * 64 + n * 16 + fr];
#pragma unroll
    for (int m = 0; m < 4; m++) {
#pragma unroll
        for (int i = 0; i < 4; i++) {
            int rl = wr * 64 + m * 16 + fq * 4 + i;
            if (rl < rcnt) {
                int grow = row_list[rstart + rl];
                float* op = out + (size_t)grow * DIM + col0 + wc * 64 + fr;
#pragma unroll
                for (int n = 0; n < 4; n++) op[n * 16] = acc[m][n][i] + bias[n];
            }
        }
    }
}

// ---------------- naive fallback (only if ws too small) --------------------
__global__ void naive_kernel(const float* __restrict__ x, const int* __restrict__ ids,
                             const float* __restrict__ W, const float* __restrict__ b,
                             float* __restrict__ out) {
    int row = blockIdx.x;
    int c = ids[row];
    __shared__ float xs[DIM];
    for (int i = threadIdx.x; i < DIM; i += 256) xs[i] = x[(size_t)row * DIM + i];
    __syncthreads();
    const float* Wc = W + (size_t)c * DIM * DIM;
    for (int o = threadIdx.x; o < DIM; o += 256) {
        float s = 0.f;
        const float* wrp = Wc + (size_t)o * DIM;
        for (int i = 0; i < DIM; i++) s += xs[i] * wrp[i];
        float bs = 0.f;
#pragma unroll
        for (int cc = 0; cc < NC; cc++) bs += b[cc * DIM + o];
        out[(size_t)row * DIM + o] = s + bs;
    }
}

extern "C" void kernel_launch(void* const* d_in, const int* in_sizes, int n_in,
                              void* d_out, int out_size, void* d_ws, size_t ws_size,
                              hipStream_t stream) {
    const float* x   = (const float*)d_in[0];
    const int*   ids = (const int*)d_in[1];
    const float* W   = (const float*)d_in[2];
    const float* b   = (const float*)d_in[3];
    float*       out = (float*)d_out;

    size_t bias_off = 0;
    size_t rl_off   = (bias_off + DIM * 4 + 255) & ~(size_t)255;
    size_t meta_off = (rl_off + B_ROWS * 4 + 255) & ~(size_t)255;
    size_t need     = meta_off + (size_t)NXCD * SLOTS * 3 * 4;

    if (ws_size < need) {
        naive_kernel<<<dim3(B_ROWS), dim3(256), 0, stream>>>(x, ids, W, b, out);
        return;
    }

    char* ws = (char*)d_ws;
    float* bias_sum = (float*)(ws + bias_off);
    int*   row_list = (int*)(ws + rl_off);
    int*   xmeta    = (int*)(ws + meta_off);

    route_kernel<<<dim3(1), dim3(1024), 0, stream>>>(ids, b, row_list, xmeta, bias_sum);
    gemm_kernel<<<dim3(NXCD, SLOTS, DIM / BN), dim3(256), 0, stream>>>(
        x, W, bias_sum, row_list, xmeta, out);
}